// Round 2
// baseline (1265.133 us; speedup 1.0000x reference)
//
#include <hip/hip_runtime.h>
#include <stdint.h>

// ---------------------------------------------------------------------------
// Problem constants
// ---------------------------------------------------------------------------
#define NB   7
#define SIN  16
#define DD   128
#define BB   32
#define TT   2048
#define TM   64          // t-rows per block (4 waves x 16 rows)
#define KMAX 31

#define XWS  24          // x window row stride (ushort) ; 24*2=48B, 16B-aligned rows
#define ZS   136         // z / bandout row stride (17*16B)
#define US   136         // u half / m row stride
#define PS   72          // p row stride (9*16B)

// ws (bf16 element offsets)
#define O_CWT 0           // [7][128][512]
#define O_W1T 458752      // [7][256][128]
#define O_W2T 688128      // [7][128][256]
#define O_PT  917504      // [7][64][128]
#define O_M1T 974848      // [128][448]
#define O_M2T 1032192     // [16][128]
#define W_TOTAL 1034240

typedef short v8s __attribute__((ext_vector_type(8)));
typedef float v4f __attribute__((ext_vector_type(4)));

__device__ __forceinline__ unsigned short f2b(float f) {
    unsigned u = __float_as_uint(f);
    u += 0x7fffu + ((u >> 16) & 1u);          // round-to-nearest-even
    return (unsigned short)(u >> 16);
}
__device__ __forceinline__ float b2f(unsigned short h) {
    return __uint_as_float(((unsigned)h) << 16);
}
__device__ __forceinline__ float gelu_fast(float x) {   // sigmoid approx (inner FFN only)
    return x / (1.f + __expf(-1.702f * x));
}
__device__ __forceinline__ float gelu_exact(float x) {  // final mix gelu
    return 0.5f * x * (1.f + erff(x * 0.70710678118654752f));
}

// ---------------------------------------------------------------------------
// Weight prep: fp32 -> bf16, transposed to B-fragment-friendly layouts
// ---------------------------------------------------------------------------
__global__ void prep_weights(const float* __restrict__ conv_w,
                             const float* __restrict__ ffn_w1,
                             const float* __restrict__ ffn_w2,
                             const float* __restrict__ proj_w,
                             const float* __restrict__ mix_w1,
                             const float* __restrict__ mix_w2,
                             unsigned short* __restrict__ wsb) {
    for (int i = blockIdx.x * 256 + threadIdx.x; i < W_TOTAL; i += gridDim.x * 256) {
        float v;
        int o = i;
        if (o < O_W1T) {                       // cwT[n][d][kf], kf = k*16+s (k==31 -> 0)
            int n = o / (128 * 512); int r = o % (128 * 512);
            int d = r / 512; int kf = r % 512;
            int k = kf >> 4, s = kf & 15;
            v = (k < KMAX) ? conv_w[((n * KMAX + k) * SIN + s) * DD + d] : 0.f;
        } else if ((o -= O_W1T) < (O_W2T - O_W1T)) {   // w1T[n][e][k] = ffn_w1[n][k][e]
            int n = o / (256 * 128); int r = o % (256 * 128);
            int e = r / 128; int k = r % 128;
            v = ffn_w1[(n * 128 + k) * 256 + e];
        } else if ((o -= (O_W2T - O_W1T)) < (O_PT - O_W2T)) { // w2T[n][d][e] = ffn_w2[n][e][d]
            int n = o / (128 * 256); int r = o % (128 * 256);
            int d = r / 256; int e = r % 256;
            v = ffn_w2[(n * 256 + e) * 128 + d];
        } else if ((o -= (O_PT - O_W2T)) < (O_M1T - O_PT)) {  // pT[n][j][k] = proj_w[n][k][j]
            int n = o / (64 * 128); int r = o % (64 * 128);
            int j = r / 128; int k = r % 128;
            v = proj_w[(n * 128 + k) * 64 + j];
        } else if ((o -= (O_M1T - O_PT)) < (O_M2T - O_M1T)) { // m1T[c][kk] = mix_w1[kk][c]
            int c = o / 448; int kk = o % 448;
            v = mix_w1[kk * 128 + c];
        } else {                                              // m2T[o16][c] = mix_w2[c][o16]
            o -= (O_M2T - O_M1T);
            int o16 = o / 128; int c = o % 128;
            v = mix_w2[c * 16 + o16];
        }
        wsb[i] = f2b(v);
    }
}

// ---------------------------------------------------------------------------
// Fused main kernel, M-split: each wave owns 16 rows x all cols.
// Zero barriers inside the band loop; all round-trips are wave-private LDS.
// ---------------------------------------------------------------------------
__global__ __launch_bounds__(256, 3)
void fused_main(const float* __restrict__ x,
                const float* __restrict__ conv_b,
                const float* __restrict__ dec_g, const float* __restrict__ dec_b,
                const float* __restrict__ n2_g,  const float* __restrict__ n2_b,
                const float* __restrict__ ffn_b1, const float* __restrict__ ffn_b2,
                const float* __restrict__ proj_b,
                const float* __restrict__ mix_b1, const float* __restrict__ mix_b2,
                const unsigned short* __restrict__ wsb,
                float* __restrict__ out) {
    __shared__ __align__(16) unsigned short xw[95 * XWS];        //  4,560 B (shared, RO after S0)
    __shared__ __align__(16) unsigned short zbs[4][16 * ZS];     // 17,408 B (wave-private)
    __shared__ __align__(16) unsigned short ubs[4][16 * US];     // 17,408 B (wave-private; u/p/m alias)

    const int tid  = threadIdx.x;
    const int lane = tid & 63;
    const int w    = tid >> 6;       // wave 0..3
    const int l16  = lane & 15;
    const int quad = lane >> 4;      // 0..3
    const int bb   = blockIdx.x >> 5;
    const int t0   = (blockIdx.x & 31) * TM;

    unsigned short* zb = zbs[w];
    unsigned short* ub = ubs[w];

    const unsigned short* cwT = wsb + O_CWT;
    const unsigned short* w1T = wsb + O_W1T;
    const unsigned short* w2T = wsb + O_W2T;
    const unsigned short* pT  = wsb + O_PT;
    const unsigned short* m1T = wsb + O_M1T;
    const unsigned short* m2T = wsb + O_M2T;

    // ---- S0: stage x window (rows t0-15 .. t0+78), bf16, shared ----
    for (int i = tid; i < 95 * SIN; i += 256) {
        int r = i >> 4, s = i & 15;
        int t = t0 + r - 15;
        float v = (t >= 0 && t < TT) ? x[((long)bb * TT + t) * SIN + s] : 0.f;
        xw[r * XWS + s] = f2b(v);
    }

    v4f macc[8];                     // persistent mix1 accumulators (all 128 cols, 16 rows)
    #pragma unroll
    for (int nt = 0; nt < 8; nt++) macc[nt] = (v4f){0.f, 0.f, 0.f, 0.f};

    __syncthreads();                 // the ONLY block-wide barrier

    static const int lo_tab[NB] = {0, 64, 128, 160, 192, 192, 224};
    static const int hi_tab[NB] = {512, 416, 384, 352, 320, 288, 288};

    const int arow = w * 16 + l16;   // this lane's A-row within the block

    for (int n = 0; n < NB; ++n) {
        unsigned hpk[16];            // h (post-LN1) packed bf16x2, rows (2rr,2rr+1) per tile

        // ================= S1: conv im2col GEMM (M=16, N=128, K=K~n) + dual LN =================
        {
            v4f hacc[8];
            #pragma unroll
            for (int nt = 0; nt < 8; nt++) hacc[nt] = (v4f){0.f, 0.f, 0.f, 0.f};
            const unsigned short* cwn = cwT + (size_t)n * 128 * 512;
            const int lo = lo_tab[n], hi = hi_tab[n];
            const int scol = (quad & 1) * 8;
            for (int kf = lo; kf < hi; kf += 32) {
                const int tap = (kf >> 4) + (quad >> 1);
                v8s a = *reinterpret_cast<const v8s*>(&xw[(arow + tap) * XWS + scol]);
                #pragma unroll
                for (int nt = 0; nt < 8; nt++) {
                    v8s bf = *reinterpret_cast<const v8s*>(
                        &cwn[(size_t)(nt * 16 + l16) * 512 + kf + quad * 8]);
                    hacc[nt] = __builtin_amdgcn_mfma_f32_16x16x32_bf16(a, bf, hacc[nt], 0, 0, 0);
                }
            }
            // biases / LN params (8 cols per lane: nt*16+l16)
            float cb[8], dg[8], db[8], ng[8], nb[8];
            #pragma unroll
            for (int nt = 0; nt < 8; nt++) {
                const int c = n * 128 + nt * 16 + l16;
                cb[nt] = conv_b[c]; dg[nt] = dec_g[c]; db[nt] = dec_b[c];
                ng[nt] = n2_g[c];   nb[nt] = n2_b[c];
            }
            float s1[4] = {0.f,0.f,0.f,0.f}, s2[4] = {0.f,0.f,0.f,0.f};
            #pragma unroll
            for (int nt = 0; nt < 8; nt++)
                #pragma unroll
                for (int r = 0; r < 4; r++) {
                    float v = hacc[nt][r] + cb[nt];
                    hacc[nt][r] = v; s1[r] += v; s2[r] += v * v;
                }
            #pragma unroll
            for (int m = 1; m <= 8; m <<= 1)
                #pragma unroll
                for (int r = 0; r < 4; r++) {
                    s1[r] += __shfl_xor(s1[r], m);
                    s2[r] += __shfl_xor(s2[r], m);
                }
            float mu[4], rs[4];
            #pragma unroll
            for (int r = 0; r < 4; r++) {
                mu[r] = s1[r] * (1.f / 128.f);
                rs[r] = rsqrtf(s2[r] * (1.f / 128.f) - mu[r] * mu[r] + 1e-5f);
            }
            float t1[4] = {0.f,0.f,0.f,0.f}, t2[4] = {0.f,0.f,0.f,0.f};
            #pragma unroll
            for (int nt = 0; nt < 8; nt++)
                #pragma unroll
                for (int r = 0; r < 4; r++) {
                    float h = (hacc[nt][r] - mu[r]) * rs[r] * dg[nt] + db[nt];
                    hacc[nt][r] = h; t1[r] += h; t2[r] += h * h;
                }
            #pragma unroll
            for (int m = 1; m <= 8; m <<= 1)
                #pragma unroll
                for (int r = 0; r < 4; r++) {
                    t1[r] += __shfl_xor(t1[r], m);
                    t2[r] += __shfl_xor(t2[r], m);
                }
            float mu2[4], rs2[4];
            #pragma unroll
            for (int r = 0; r < 4; r++) {
                mu2[r] = t1[r] * (1.f / 128.f);
                rs2[r] = rsqrtf(t2[r] * (1.f / 128.f) - mu2[r] * mu2[r] + 1e-5f);
            }
            // write z (A-layout source) + pack h to bf16 pairs
            #pragma unroll
            for (int nt = 0; nt < 8; nt++) {
                #pragma unroll
                for (int rr = 0; rr < 2; rr++) {
                    float h0 = hacc[nt][2 * rr],     h1 = hacc[nt][2 * rr + 1];
                    hpk[nt * 2 + rr] = (unsigned)f2b(h0) | ((unsigned)f2b(h1) << 16);
                }
                #pragma unroll
                for (int r = 0; r < 4; r++) {
                    float z = (hacc[nt][r] - mu2[r]) * rs2[r] * ng[nt] + nb[nt];
                    zb[(quad * 4 + r) * ZS + nt * 16 + l16] = f2b(z);
                }
            }
        }

        // ================= S3/S4: FFN1+gelu / FFN2, e-split halves, K=128 each =================
        v4f acc2[8];
        #pragma unroll
        for (int dt = 0; dt < 8; dt++) acc2[dt] = (v4f){0.f, 0.f, 0.f, 0.f};
        #pragma unroll
        for (int eh = 0; eh < 2; ++eh) {
            v4f ua[8];
            #pragma unroll
            for (int nt = 0; nt < 8; nt++) ua[nt] = (v4f){0.f, 0.f, 0.f, 0.f};
            const unsigned short* w1n = w1T + ((size_t)n * 256 + eh * 128) * 128;
            #pragma unroll
            for (int kb = 0; kb < 128; kb += 32) {
                v8s a = *reinterpret_cast<const v8s*>(&zb[l16 * ZS + kb + quad * 8]);
                #pragma unroll
                for (int nt = 0; nt < 8; nt++) {
                    v8s bf = *reinterpret_cast<const v8s*>(
                        &w1n[(size_t)(nt * 16 + l16) * 128 + kb + quad * 8]);
                    ua[nt] = __builtin_amdgcn_mfma_f32_16x16x32_bf16(a, bf, ua[nt], 0, 0, 0);
                }
            }
            #pragma unroll
            for (int nt = 0; nt < 8; nt++) {
                const float b1 = ffn_b1[n * 256 + eh * 128 + nt * 16 + l16];
                #pragma unroll
                for (int r = 0; r < 4; r++)
                    ub[(quad * 4 + r) * US + nt * 16 + l16] = f2b(gelu_fast(ua[nt][r] + b1));
            }
            const unsigned short* w2n = w2T + (size_t)n * 128 * 256 + eh * 128;
            #pragma unroll
            for (int kb = 0; kb < 128; kb += 32) {
                v8s a = *reinterpret_cast<const v8s*>(&ub[l16 * US + kb + quad * 8]);
                #pragma unroll
                for (int dt = 0; dt < 8; dt++) {
                    v8s bf = *reinterpret_cast<const v8s*>(
                        &w2n[(size_t)(dt * 16 + l16) * 256 + kb + quad * 8]);
                    acc2[dt] = __builtin_amdgcn_mfma_f32_16x16x32_bf16(a, bf, acc2[dt], 0, 0, 0);
                }
            }
        }

        // ================= band_out = acc2 + b2 + h  -> zb =================
        #pragma unroll
        for (int dt = 0; dt < 8; dt++) {
            const float b2v = ffn_b2[n * 128 + dt * 16 + l16];
            #pragma unroll
            for (int rr = 0; rr < 2; rr++) {
                unsigned hp = hpk[dt * 2 + rr];
                float h0 = __uint_as_float(hp << 16);
                float h1 = __uint_as_float(hp & 0xffff0000u);
                float bo0 = acc2[dt][2 * rr]     + b2v + h0;
                float bo1 = acc2[dt][2 * rr + 1] + b2v + h1;
                zb[(quad * 4 + 2 * rr)     * ZS + dt * 16 + l16] = f2b(bo0);
                zb[(quad * 4 + 2 * rr + 1) * ZS + dt * 16 + l16] = f2b(bo1);
            }
        }

        // ================= S5: proj (M=16, N=64, K=128) -> pb =================
        {
            v4f pa[4];
            #pragma unroll
            for (int jt = 0; jt < 4; jt++) pa[jt] = (v4f){0.f, 0.f, 0.f, 0.f};
            const unsigned short* pn = pT + (size_t)n * 64 * 128;
            #pragma unroll
            for (int kb = 0; kb < 128; kb += 32) {
                v8s a = *reinterpret_cast<const v8s*>(&zb[l16 * ZS + kb + quad * 8]);
                #pragma unroll
                for (int jt = 0; jt < 4; jt++) {
                    v8s bf = *reinterpret_cast<const v8s*>(
                        &pn[(size_t)(jt * 16 + l16) * 128 + kb + quad * 8]);
                    pa[jt] = __builtin_amdgcn_mfma_f32_16x16x32_bf16(a, bf, pa[jt], 0, 0, 0);
                }
            }
            #pragma unroll
            for (int jt = 0; jt < 4; jt++) {
                const float pbv = proj_b[n * 64 + jt * 16 + l16];
                #pragma unroll
                for (int r = 0; r < 4; r++)
                    ub[(quad * 4 + r) * PS + jt * 16 + l16] = f2b(pa[jt][r] + pbv);
            }
        }

        // ================= S6: mix1 partial accumulate (K=64) =================
        {
            const unsigned short* m1n = m1T + n * 64;
            #pragma unroll
            for (int kb = 0; kb < 64; kb += 32) {
                v8s a = *reinterpret_cast<const v8s*>(&ub[l16 * PS + kb + quad * 8]);
                #pragma unroll
                for (int nt = 0; nt < 8; nt++) {
                    v8s bf = *reinterpret_cast<const v8s*>(
                        &m1n[(size_t)(nt * 16 + l16) * 448 + kb + quad * 8]);
                    macc[nt] = __builtin_amdgcn_mfma_f32_16x16x32_bf16(a, bf, macc[nt], 0, 0, 0);
                }
            }
        }
    }

    // ================= S7: m = gelu(macc + b1) -> ub =================
    #pragma unroll
    for (int nt = 0; nt < 8; nt++) {
        const float mb1 = mix_b1[nt * 16 + l16];
        #pragma unroll
        for (int r = 0; r < 4; r++)
            ub[(quad * 4 + r) * US + nt * 16 + l16] = f2b(gelu_exact(macc[nt][r] + mb1));
    }

    // ================= S8: mix2 (M=16, N=16, K=128) -> out =================
    {
        v4f oacc = (v4f){0.f, 0.f, 0.f, 0.f};
        #pragma unroll
        for (int kb = 0; kb < 128; kb += 32) {
            v8s a  = *reinterpret_cast<const v8s*>(&ub[l16 * US + kb + quad * 8]);
            v8s bf = *reinterpret_cast<const v8s*>(&m2T[(size_t)l16 * 128 + kb + quad * 8]);
            oacc = __builtin_amdgcn_mfma_f32_16x16x32_bf16(a, bf, oacc, 0, 0, 0);
        }
        const float ob = mix_b2[l16];
        #pragma unroll
        for (int r = 0; r < 4; r++) {
            const int row = w * 16 + quad * 4 + r;
            out[((long)bb * TT + t0 + row) * SIN + l16] = oacc[r] + ob;
        }
    }
}

// ---------------------------------------------------------------------------
extern "C" void kernel_launch(void* const* d_in, const int* in_sizes, int n_in,
                              void* d_out, int out_size, void* d_ws, size_t ws_size,
                              hipStream_t stream) {
    (void)in_sizes; (void)n_in; (void)out_size; (void)ws_size;
    const float* x      = (const float*)d_in[0];
    const float* conv_w = (const float*)d_in[1];
    const float* conv_b = (const float*)d_in[2];
    const float* dec_g  = (const float*)d_in[3];
    const float* dec_b  = (const float*)d_in[4];
    const float* n2_g   = (const float*)d_in[5];
    const float* n2_b   = (const float*)d_in[6];
    const float* ffn_w1 = (const float*)d_in[7];
    const float* ffn_b1 = (const float*)d_in[8];
    const float* ffn_w2 = (const float*)d_in[9];
    const float* ffn_b2 = (const float*)d_in[10];
    const float* proj_w = (const float*)d_in[11];
    const float* proj_b = (const float*)d_in[12];
    const float* mix_w1 = (const float*)d_in[13];
    const float* mix_b1 = (const float*)d_in[14];
    const float* mix_w2 = (const float*)d_in[15];
    const float* mix_b2 = (const float*)d_in[16];
    unsigned short* wsb = (unsigned short*)d_ws;
    float* out = (float*)d_out;

    hipLaunchKernelGGL(prep_weights, dim3(1024), dim3(256), 0, stream,
                       conv_w, ffn_w1, ffn_w2, proj_w, mix_w1, mix_w2, wsb);
    hipLaunchKernelGGL(fused_main, dim3(BB * (TT / TM)), dim3(256), 0, stream,
                       x, conv_b, dec_g, dec_b, n2_g, n2_b, ffn_b1, ffn_b2,
                       proj_b, mix_b1, mix_b2, wsb, out);
}

// Round 3
// 857.439 us; speedup vs baseline: 1.4755x; 1.4755x over previous
//
#include <hip/hip_runtime.h>
#include <stdint.h>

// ---------------------------------------------------------------------------
// Problem constants
// ---------------------------------------------------------------------------
#define NB   7
#define SIN  16
#define DD   128
#define BB   32
#define TT   2048
#define TM   64          // t-rows per block (4 waves x 16 rows)
#define KMAX 31

#define XWS  24          // x window row stride (ushort); 48B rows, 16B-aligned
#define ZS   136         // z / bandout row stride (17*16B)
#define US   136         // u half / m row stride
#define PS   72          // p row stride (9*16B)

// ws (bf16 element offsets)
#define O_CWT 0           // [7][128][512]
#define O_W1T 458752      // [7][256][128]
#define O_W2T 688128      // [7][128][256]
#define O_PT  917504      // [7][64][128]
#define O_M1T 974848      // [128][448]
#define O_M2T 1032192     // [16][128]

typedef short v8s __attribute__((ext_vector_type(8)));
typedef float v4f __attribute__((ext_vector_type(4)));

__device__ __forceinline__ unsigned short f2b(float f) {
    unsigned u = __float_as_uint(f);
    u += 0x7fffu + ((u >> 16) & 1u);          // round-to-nearest-even
    return (unsigned short)(u >> 16);
}
__device__ __forceinline__ float gelu_fast(float x) {   // sigmoid approx (inner FFN only)
    return x / (1.f + __expf(-1.702f * x));
}
__device__ __forceinline__ float gelu_exact(float x) {  // final mix gelu
    return 0.5f * x * (1.f + erff(x * 0.70710678118654752f));
}

// ---------------------------------------------------------------------------
// Weight prep: LDS-tiled fp32->bf16 transposes (all 6 layouts are pure 2D
// transposes per matrix). 32x32 tiles, 256 threads (32x8).
// ---------------------------------------------------------------------------
// jobs: {tileStart, tilesPerMat, tR, tC, R, C, Rpad, nmat, srcStride, dstOff, dstStride}
// cw : src [496x128] x7 -> dst [128x512] (cols 496..511 zero)
// w1 : src [128x256] x7 -> dst [256x128]
// w2 : src [256x128] x7 -> dst [128x256]
// pT : src [128x 64] x7 -> dst [ 64x128]
// m1 : src [448x128] x1 -> dst [128x448]
// m2 : src [128x 16] x1 -> dst [ 16x128]
#define PREP_TILES 1012

__global__ __launch_bounds__(256)
void prep_weights(const float* __restrict__ conv_w,
                  const float* __restrict__ ffn_w1,
                  const float* __restrict__ ffn_w2,
                  const float* __restrict__ proj_w,
                  const float* __restrict__ mix_w1,
                  const float* __restrict__ mix_w2,
                  unsigned short* __restrict__ wsb) {
    __shared__ float tile[32][33];
    const int bid = blockIdx.x;
    const int tx = threadIdx.x & 31, ty = threadIdx.x >> 5;   // 32 x 8

    const float* src; int R, C, Rpad, tC, tilesPerMat, mat, tix, dstOff, dstStride;
    if (bid < 448)        { src = conv_w; R = 496; C = 128; Rpad = 512; tC = 4; tilesPerMat = 64;
                            mat = bid / 64;          tix = bid % 64;  dstOff = O_CWT; dstStride = 0; }
    else if (bid < 672)   { src = ffn_w1; R = 128; C = 256; Rpad = 128; tC = 8; tilesPerMat = 32;
                            mat = (bid - 448) / 32;  tix = (bid - 448) % 32; dstOff = O_W1T; dstStride = 0; }
    else if (bid < 896)   { src = ffn_w2; R = 256; C = 128; Rpad = 256; tC = 4; tilesPerMat = 32;
                            mat = (bid - 672) / 32;  tix = (bid - 672) % 32; dstOff = O_W2T; dstStride = 0; }
    else if (bid < 952)   { src = proj_w; R = 128; C = 64;  Rpad = 128; tC = 2; tilesPerMat = 8;
                            mat = (bid - 896) / 8;   tix = (bid - 896) % 8;  dstOff = O_PT;  dstStride = 0; }
    else if (bid < 1008)  { src = mix_w1; R = 448; C = 128; Rpad = 448; tC = 4; tilesPerMat = 56;
                            mat = 0;                 tix = bid - 952;  dstOff = O_M1T; dstStride = 0; }
    else                  { src = mix_w2; R = 128; C = 16;  Rpad = 128; tC = 1; tilesPerMat = 4;
                            mat = 0;                 tix = bid - 1008; dstOff = O_M2T; dstStride = 0; }
    (void)tilesPerMat; (void)dstStride;

    const int tileR = tix / tC, tileC = tix % tC;
    const float* s = src + (size_t)mat * R * C;
    unsigned short* d = wsb + dstOff + (size_t)mat * C * Rpad;

    #pragma unroll
    for (int i = 0; i < 4; i++) {
        int r = tileR * 32 + ty + i * 8;
        int c = tileC * 32 + tx;
        tile[ty + i * 8][tx] = (r < R && c < C) ? s[(size_t)r * C + c] : 0.f;
    }
    __syncthreads();
    #pragma unroll
    for (int i = 0; i < 4; i++) {
        int dr = tileC * 32 + ty + i * 8;   // dst row = src col
        int dc = tileR * 32 + tx;           // dst col = src row (incl zero pad)
        if (dr < C) d[(size_t)dr * Rpad + dc] = f2b(tile[tx][ty + i * 8]);
    }
}

// ---------------------------------------------------------------------------
// Fused main kernel, M-split: each wave owns 16 rows x all cols.
// Zero barriers inside the band loop; all round-trips are wave-private LDS.
// ---------------------------------------------------------------------------
__global__ __launch_bounds__(256, 2)
void fused_main(const float* __restrict__ x,
                const float* __restrict__ conv_b,
                const float* __restrict__ dec_g, const float* __restrict__ dec_b,
                const float* __restrict__ n2_g,  const float* __restrict__ n2_b,
                const float* __restrict__ ffn_b1, const float* __restrict__ ffn_b2,
                const float* __restrict__ proj_b,
                const float* __restrict__ mix_b1, const float* __restrict__ mix_b2,
                const unsigned short* __restrict__ wsb,
                float* __restrict__ out) {
    __shared__ __align__(16) unsigned short xw[95 * XWS];        //  4,560 B (shared, RO after S0)
    __shared__ __align__(16) unsigned short zbs[4][16 * ZS];     // 17,408 B (wave-private)
    __shared__ __align__(16) unsigned short ubs[4][16 * US];     // 17,408 B (wave-private; u/p/m alias)

    const int tid  = threadIdx.x;
    const int lane = tid & 63;
    const int w    = tid >> 6;       // wave 0..3
    const int l16  = lane & 15;
    const int quad = lane >> 4;      // 0..3
    const int bb   = blockIdx.x >> 5;
    const int t0   = (blockIdx.x & 31) * TM;

    unsigned short* zb = zbs[w];
    unsigned short* ub = ubs[w];

    const unsigned short* cwT = wsb + O_CWT;
    const unsigned short* w1T = wsb + O_W1T;
    const unsigned short* w2T = wsb + O_W2T;
    const unsigned short* pT  = wsb + O_PT;
    const unsigned short* m1T = wsb + O_M1T;
    const unsigned short* m2T = wsb + O_M2T;

    // ---- S0: stage x window (rows t0-15 .. t0+78), bf16, shared ----
    for (int i = tid; i < 95 * SIN; i += 256) {
        int r = i >> 4, s = i & 15;
        int t = t0 + r - 15;
        float v = (t >= 0 && t < TT) ? x[((long)bb * TT + t) * SIN + s] : 0.f;
        xw[r * XWS + s] = f2b(v);
    }

    v4f macc[8];                     // persistent mix1 accumulators (all 128 cols, 16 rows)
    #pragma unroll
    for (int nt = 0; nt < 8; nt++) macc[nt] = (v4f){0.f, 0.f, 0.f, 0.f};

    __syncthreads();                 // the ONLY block-wide barrier

    static const int lo_tab[NB] = {0, 64, 128, 160, 192, 192, 224};
    static const int hi_tab[NB] = {512, 416, 384, 352, 320, 288, 288};

    const int arow = w * 16 + l16;   // this lane's A-row within the block

    for (int n = 0; n < NB; ++n) {
        unsigned hpk[16];            // h (post-LN1) packed bf16x2, rows (2rr,2rr+1) per tile

        // ================= S1: conv im2col GEMM (M=16, N=128, K=K~n) + dual LN =================
        {
            v4f hacc[8];
            #pragma unroll
            for (int nt = 0; nt < 8; nt++) hacc[nt] = (v4f){0.f, 0.f, 0.f, 0.f};
            const unsigned short* cwn = cwT + (size_t)n * 128 * 512;
            const int lo = lo_tab[n], hi = hi_tab[n];
            const int scol = (quad & 1) * 8;
            for (int kf = lo; kf < hi; kf += 32) {
                const int tap = (kf >> 4) + (quad >> 1);
                v8s a = *reinterpret_cast<const v8s*>(&xw[(arow + tap) * XWS + scol]);
                #pragma unroll
                for (int nt = 0; nt < 8; nt++) {
                    v8s bf = *reinterpret_cast<const v8s*>(
                        &cwn[(size_t)(nt * 16 + l16) * 512 + kf + quad * 8]);
                    hacc[nt] = __builtin_amdgcn_mfma_f32_16x16x32_bf16(a, bf, hacc[nt], 0, 0, 0);
                }
            }
            // conv bias + LN1 stats (lazy bias loads: short register lifetimes)
            float s1[4] = {0.f,0.f,0.f,0.f}, s2[4] = {0.f,0.f,0.f,0.f};
            #pragma unroll
            for (int nt = 0; nt < 8; nt++) {
                const float cb = conv_b[n * 128 + nt * 16 + l16];
                #pragma unroll
                for (int r = 0; r < 4; r++) {
                    float v = hacc[nt][r] + cb;
                    hacc[nt][r] = v; s1[r] += v; s2[r] += v * v;
                }
            }
            #pragma unroll
            for (int m = 1; m <= 8; m <<= 1)
                #pragma unroll
                for (int r = 0; r < 4; r++) {
                    s1[r] += __shfl_xor(s1[r], m);
                    s2[r] += __shfl_xor(s2[r], m);
                }
            float mu[4], rs[4];
            #pragma unroll
            for (int r = 0; r < 4; r++) {
                mu[r] = s1[r] * (1.f / 128.f);
                rs[r] = rsqrtf(s2[r] * (1.f / 128.f) - mu[r] * mu[r] + 1e-5f);
            }
            float t1[4] = {0.f,0.f,0.f,0.f}, t2[4] = {0.f,0.f,0.f,0.f};
            #pragma unroll
            for (int nt = 0; nt < 8; nt++) {
                const float dg = dec_g[n * 128 + nt * 16 + l16];
                const float db = dec_b[n * 128 + nt * 16 + l16];
                #pragma unroll
                for (int r = 0; r < 4; r++) {
                    float h = (hacc[nt][r] - mu[r]) * rs[r] * dg + db;
                    hacc[nt][r] = h; t1[r] += h; t2[r] += h * h;
                }
            }
            #pragma unroll
            for (int m = 1; m <= 8; m <<= 1)
                #pragma unroll
                for (int r = 0; r < 4; r++) {
                    t1[r] += __shfl_xor(t1[r], m);
                    t2[r] += __shfl_xor(t2[r], m);
                }
            float mu2[4], rs2[4];
            #pragma unroll
            for (int r = 0; r < 4; r++) {
                mu2[r] = t1[r] * (1.f / 128.f);
                rs2[r] = rsqrtf(t2[r] * (1.f / 128.f) - mu2[r] * mu2[r] + 1e-5f);
            }
            // write z (A-layout source) + pack h to bf16 pairs
            #pragma unroll
            for (int nt = 0; nt < 8; nt++) {
                const float ng = n2_g[n * 128 + nt * 16 + l16];
                const float nb = n2_b[n * 128 + nt * 16 + l16];
                #pragma unroll
                for (int rr = 0; rr < 2; rr++) {
                    float h0 = hacc[nt][2 * rr],     h1 = hacc[nt][2 * rr + 1];
                    hpk[nt * 2 + rr] = (unsigned)f2b(h0) | ((unsigned)f2b(h1) << 16);
                }
                #pragma unroll
                for (int r = 0; r < 4; r++) {
                    float z = (hacc[nt][r] - mu2[r]) * rs2[r] * ng + nb;
                    zb[(quad * 4 + r) * ZS + nt * 16 + l16] = f2b(z);
                }
            }
        }

        // ================= S3/S4: FFN1+gelu / FFN2, e-split halves, K=128 each =================
        v4f acc2[8];
        #pragma unroll
        for (int dt = 0; dt < 8; dt++) acc2[dt] = (v4f){0.f, 0.f, 0.f, 0.f};
        #pragma unroll
        for (int eh = 0; eh < 2; ++eh) {
            v4f ua[8];
            #pragma unroll
            for (int nt = 0; nt < 8; nt++) ua[nt] = (v4f){0.f, 0.f, 0.f, 0.f};
            const unsigned short* w1n = w1T + ((size_t)n * 256 + eh * 128) * 128;
            #pragma unroll
            for (int kb = 0; kb < 128; kb += 32) {
                v8s a = *reinterpret_cast<const v8s*>(&zb[l16 * ZS + kb + quad * 8]);
                #pragma unroll
                for (int nt = 0; nt < 8; nt++) {
                    v8s bf = *reinterpret_cast<const v8s*>(
                        &w1n[(size_t)(nt * 16 + l16) * 128 + kb + quad * 8]);
                    ua[nt] = __builtin_amdgcn_mfma_f32_16x16x32_bf16(a, bf, ua[nt], 0, 0, 0);
                }
            }
            #pragma unroll
            for (int nt = 0; nt < 8; nt++) {
                const float b1 = ffn_b1[n * 256 + eh * 128 + nt * 16 + l16];
                #pragma unroll
                for (int r = 0; r < 4; r++)
                    ub[(quad * 4 + r) * US + nt * 16 + l16] = f2b(gelu_fast(ua[nt][r] + b1));
            }
            const unsigned short* w2n = w2T + (size_t)n * 128 * 256 + eh * 128;
            #pragma unroll
            for (int kb = 0; kb < 128; kb += 32) {
                v8s a = *reinterpret_cast<const v8s*>(&ub[l16 * US + kb + quad * 8]);
                #pragma unroll
                for (int dt = 0; dt < 8; dt++) {
                    v8s bf = *reinterpret_cast<const v8s*>(
                        &w2n[(size_t)(dt * 16 + l16) * 256 + kb + quad * 8]);
                    acc2[dt] = __builtin_amdgcn_mfma_f32_16x16x32_bf16(a, bf, acc2[dt], 0, 0, 0);
                }
            }
        }

        // ================= band_out = acc2 + b2 + h  -> zb =================
        #pragma unroll
        for (int dt = 0; dt < 8; dt++) {
            const float b2v = ffn_b2[n * 128 + dt * 16 + l16];
            #pragma unroll
            for (int rr = 0; rr < 2; rr++) {
                unsigned hp = hpk[dt * 2 + rr];
                float h0 = __uint_as_float(hp << 16);
                float h1 = __uint_as_float(hp & 0xffff0000u);
                float bo0 = acc2[dt][2 * rr]     + b2v + h0;
                float bo1 = acc2[dt][2 * rr + 1] + b2v + h1;
                zb[(quad * 4 + 2 * rr)     * ZS + dt * 16 + l16] = f2b(bo0);
                zb[(quad * 4 + 2 * rr + 1) * ZS + dt * 16 + l16] = f2b(bo1);
            }
        }

        // ================= S5: proj (M=16, N=64, K=128) -> pb =================
        {
            v4f pa[4];
            #pragma unroll
            for (int jt = 0; jt < 4; jt++) pa[jt] = (v4f){0.f, 0.f, 0.f, 0.f};
            const unsigned short* pn = pT + (size_t)n * 64 * 128;
            #pragma unroll
            for (int kb = 0; kb < 128; kb += 32) {
                v8s a = *reinterpret_cast<const v8s*>(&zb[l16 * ZS + kb + quad * 8]);
                #pragma unroll
                for (int jt = 0; jt < 4; jt++) {
                    v8s bf = *reinterpret_cast<const v8s*>(
                        &pn[(size_t)(jt * 16 + l16) * 128 + kb + quad * 8]);
                    pa[jt] = __builtin_amdgcn_mfma_f32_16x16x32_bf16(a, bf, pa[jt], 0, 0, 0);
                }
            }
            #pragma unroll
            for (int jt = 0; jt < 4; jt++) {
                const float pbv = proj_b[n * 64 + jt * 16 + l16];
                #pragma unroll
                for (int r = 0; r < 4; r++)
                    ub[(quad * 4 + r) * PS + jt * 16 + l16] = f2b(pa[jt][r] + pbv);
            }
        }

        // ================= S6: mix1 partial accumulate (K=64) =================
        {
            const unsigned short* m1n = m1T + n * 64;
            #pragma unroll
            for (int kb = 0; kb < 64; kb += 32) {
                v8s a = *reinterpret_cast<const v8s*>(&ub[l16 * PS + kb + quad * 8]);
                #pragma unroll
                for (int nt = 0; nt < 8; nt++) {
                    v8s bf = *reinterpret_cast<const v8s*>(
                        &m1n[(size_t)(nt * 16 + l16) * 448 + kb + quad * 8]);
                    macc[nt] = __builtin_amdgcn_mfma_f32_16x16x32_bf16(a, bf, macc[nt], 0, 0, 0);
                }
            }
        }
    }

    // ================= S7: m = gelu(macc + b1) -> ub =================
    #pragma unroll
    for (int nt = 0; nt < 8; nt++) {
        const float mb1 = mix_b1[nt * 16 + l16];
        #pragma unroll
        for (int r = 0; r < 4; r++)
            ub[(quad * 4 + r) * US + nt * 16 + l16] = f2b(gelu_exact(macc[nt][r] + mb1));
    }

    // ================= S8: mix2 (M=16, N=16, K=128) -> out =================
    {
        v4f oacc = (v4f){0.f, 0.f, 0.f, 0.f};
        #pragma unroll
        for (int kb = 0; kb < 128; kb += 32) {
            v8s a  = *reinterpret_cast<const v8s*>(&ub[l16 * US + kb + quad * 8]);
            v8s bf = *reinterpret_cast<const v8s*>(&m2T[(size_t)l16 * 128 + kb + quad * 8]);
            oacc = __builtin_amdgcn_mfma_f32_16x16x32_bf16(a, bf, oacc, 0, 0, 0);
        }
        const float ob = mix_b2[l16];
        #pragma unroll
        for (int r = 0; r < 4; r++) {
            const int row = w * 16 + quad * 4 + r;
            out[((long)bb * TT + t0 + row) * SIN + l16] = oacc[r] + ob;
        }
    }
}

// ---------------------------------------------------------------------------
extern "C" void kernel_launch(void* const* d_in, const int* in_sizes, int n_in,
                              void* d_out, int out_size, void* d_ws, size_t ws_size,
                              hipStream_t stream) {
    (void)in_sizes; (void)n_in; (void)out_size; (void)ws_size;
    const float* x      = (const float*)d_in[0];
    const float* conv_w = (const float*)d_in[1];
    const float* conv_b = (const float*)d_in[2];
    const float* dec_g  = (const float*)d_in[3];
    const float* dec_b  = (const float*)d_in[4];
    const float* n2_g   = (const float*)d_in[5];
    const float* n2_b   = (const float*)d_in[6];
    const float* ffn_w1 = (const float*)d_in[7];
    const float* ffn_b1 = (const float*)d_in[8];
    const float* ffn_w2 = (const float*)d_in[9];
    const float* ffn_b2 = (const float*)d_in[10];
    const float* proj_w = (const float*)d_in[11];
    const float* proj_b = (const float*)d_in[12];
    const float* mix_w1 = (const float*)d_in[13];
    const float* mix_b1 = (const float*)d_in[14];
    const float* mix_w2 = (const float*)d_in[15];
    const float* mix_b2 = (const float*)d_in[16];
    unsigned short* wsb = (unsigned short*)d_ws;
    float* out = (float*)d_out;

    hipLaunchKernelGGL(prep_weights, dim3(PREP_TILES), dim3(256), 0, stream,
                       conv_w, ffn_w1, ffn_w2, proj_w, mix_w1, mix_w2, wsb);
    hipLaunchKernelGGL(fused_main, dim3(BB * (TT / TM)), dim3(256), 0, stream,
                       x, conv_b, dec_g, dec_b, n2_g, n2_b, ffn_b1, ffn_b2,
                       proj_b, mix_b1, mix_b2, wsb, out);
}

// Round 4
// 751.330 us; speedup vs baseline: 1.6839x; 1.1412x over previous
//
#include <hip/hip_runtime.h>
#include <stdint.h>

// ---------------------------------------------------------------------------
// Problem constants
// ---------------------------------------------------------------------------
#define NB   7
#define SIN  16
#define DD   128
#define BB   32
#define TT   2048
#define TM   64          // t-rows per block (4 waves, N-split over cols)
#define KMAX 31

#define XWS  24          // x window row stride (ushort); 48B rows
#define ZS   136         // z / bandout row stride
#define US   136         // u-half row stride (also m buffer)
#define PS   72          // p row stride

// Fragment-linear weight regions (ushort element offsets in ws).
// Every 512-element chunk is one wave B-fragment: [lane(64)][j(8)].
#define O_CWF 0           // [7][ntile 8][kc 16][512]
#define O_W1F 458752      // [7][etile 16][kb 4][512]
#define O_W2F 688128      // [7][dtile 8][kc 8][512]
#define O_PF  917504      // [7][jtile 4][kb 4][512]
#define O_M1F 974848      // [ctile 8][band 7][kc 2][512]
#define O_M2F 1032192     // [kb 4][512]
#define W_TOTAL 1034240

typedef short v8s __attribute__((ext_vector_type(8)));
typedef float v4f __attribute__((ext_vector_type(4)));

__device__ __forceinline__ unsigned short f2b(float f) {
    unsigned u = __float_as_uint(f);
    u += 0x7fffu + ((u >> 16) & 1u);          // round-to-nearest-even
    return (unsigned short)(u >> 16);
}
__device__ __forceinline__ float gelu_fast(float x) {   // sigmoid approx (inner FFN only)
    return x / (1.f + __expf(-1.702f * x));
}
__device__ __forceinline__ float gelu_exact(float x) {  // final mix gelu
    return 0.5f * x * (1.f + erff(x * 0.70710678118654752f));
}

// ---------------------------------------------------------------------------
// Weight prep: fp32 -> bf16, gathered into fragment-linear layout.
// Output element i (region,frag,lane,j) -> source element. Grid-stride.
// ---------------------------------------------------------------------------
__global__ __launch_bounds__(256)
void prep_weights(const float* __restrict__ conv_w,
                  const float* __restrict__ ffn_w1,
                  const float* __restrict__ ffn_w2,
                  const float* __restrict__ proj_w,
                  const float* __restrict__ mix_w1,
                  const float* __restrict__ mix_w2,
                  unsigned short* __restrict__ wsb) {
    for (int i = blockIdx.x * 256 + threadIdx.x; i < W_TOTAL; i += gridDim.x * 256) {
        int o = i;
        int t9 = o & 511, j = t9 & 7, ln = t9 >> 3;
        int q = ln >> 4, l = ln & 15;
        float v;
        if (o < O_W1F) {                                   // conv
            int f = o >> 9;
            int band = f >> 7, rem = f & 127, ntile = rem >> 4, kc = rem & 15;
            int kg = kc * 32 + q * 8 + j, tap = kg >> 4, s = kg & 15, d = ntile * 16 + l;
            v = (tap < KMAX) ? conv_w[((band * KMAX + tap) * SIN + s) * DD + d] : 0.f;
        } else if (o < O_W2F) {                            // ffn_w1
            int f = (o - O_W1F) >> 9;
            int band = f >> 6, rem = f & 63, et = rem >> 2, kb = rem & 3;
            int k = kb * 32 + q * 8 + j, e = et * 16 + l;
            v = ffn_w1[(band * 128 + k) * 256 + e];
        } else if (o < O_PF) {                             // ffn_w2
            int f = (o - O_W2F) >> 9;
            int band = f >> 6, rem = f & 63, dt = rem >> 3, kc = rem & 7;
            int k = kc * 32 + q * 8 + j, d = dt * 16 + l;
            v = ffn_w2[(band * 256 + k) * 128 + d];
        } else if (o < O_M1F) {                            // proj
            int f = (o - O_PF) >> 9;
            int band = f >> 4, rem = f & 15, jt = rem >> 2, kb = rem & 3;
            int k = kb * 32 + q * 8 + j, c = jt * 16 + l;
            v = proj_w[(band * 128 + k) * 64 + c];
        } else if (o < O_M2F) {                            // mix_w1
            int f = (o - O_M1F) >> 9;
            int ct = f / 14, rem = f % 14, band = rem >> 1, kc = rem & 1;
            int k = band * 64 + kc * 32 + q * 8 + j, c = ct * 16 + l;
            v = mix_w1[k * 128 + c];
        } else {                                           // mix_w2
            int f = (o - O_M2F) >> 9;
            int k = f * 32 + q * 8 + j;
            v = mix_w2[k * SIN + l];
        }
        wsb[i] = f2b(v);
    }
}

// ---------------------------------------------------------------------------
// Fused main kernel. N-split: wave w owns cols w*32..w*32+31 of every stage
// (e-tiles 2w,2w+1 per FFN half; proj j-tile w; mix c-tiles 2w,2w+1).
// LN stats via 2-float cross-wave partials; h/hn stay in registers.
// ---------------------------------------------------------------------------
__global__ __launch_bounds__(256, 3)
void fused_main(const float* __restrict__ x,
                const float* __restrict__ conv_b,
                const float* __restrict__ dec_g, const float* __restrict__ dec_b,
                const float* __restrict__ n2_g,  const float* __restrict__ n2_b,
                const float* __restrict__ ffn_b1, const float* __restrict__ ffn_b2,
                const float* __restrict__ proj_b,
                const float* __restrict__ mix_b1, const float* __restrict__ mix_b2,
                const unsigned short* __restrict__ wsb,
                float* __restrict__ out) {
    __shared__ __align__(16) unsigned short xw[95 * XWS];     //  4,560 B
    __shared__ __align__(16) unsigned short zbuf[TM * ZS];    // 17,408 B (z / band_out)
    __shared__ __align__(16) unsigned short ubuf[TM * US];    // 17,408 B (u-half / p / m)
    __shared__ __align__(16) float part1[TM * 8];             //  2,048 B
    __shared__ __align__(16) float part2[TM * 8];             //  2,048 B

    const int tid  = threadIdx.x;
    const int lane = tid & 63;
    const int w    = tid >> 6;       // wave 0..3
    const int l16  = lane & 15;
    const int quad = lane >> 4;      // 0..3
    const int bb   = blockIdx.x >> 5;
    const int t0   = (blockIdx.x & 31) * TM;

    const unsigned short* cwF = wsb + O_CWF + lane * 8;
    const unsigned short* w1F = wsb + O_W1F + lane * 8;
    const unsigned short* w2F = wsb + O_W2F + lane * 8;
    const unsigned short* pF  = wsb + O_PF  + lane * 8;
    const unsigned short* m1F = wsb + O_M1F + lane * 8;
    const unsigned short* m2F = wsb + O_M2F + lane * 8;

    // ---- S0: stage x window (rows t0-15 .. t0+78), bf16 ----
    for (int i = tid; i < 95 * SIN; i += 256) {
        int r = i >> 4, s = i & 15;
        int t = t0 + r - 15;
        float v = (t >= 0 && t < TT) ? x[((long)bb * TT + t) * SIN + s] : 0.f;
        xw[r * XWS + s] = f2b(v);
    }

    v4f macc[4][2];                  // persistent mix1 accumulators (ctiles 2w,2w+1)
    #pragma unroll
    for (int mt = 0; mt < 4; mt++)
        #pragma unroll
        for (int c = 0; c < 2; c++) macc[mt][c] = (v4f){0.f, 0.f, 0.f, 0.f};

    __syncthreads();

    static const int lo_kc[NB] = {0, 2, 4, 5, 6, 6, 7};
    static const int hi_kc[NB] = {16, 13, 12, 11, 10, 9, 9};

    const int col0 = w * 32 + l16;       // nt=0 col for this lane
    const int col1 = col0 + 16;          // nt=1 col

    for (int n = 0; n < NB; ++n) {
        unsigned hpk[16];                // packed hn (residual), [mt*4+r] = (hn0 | hn1<<16)
        v4f acc[4][2];                   // conv C-frags -> h -> hn (in regs)
        #pragma unroll
        for (int mt = 0; mt < 4; mt++)
            #pragma unroll
            for (int c = 0; c < 2; c++) acc[mt][c] = (v4f){0.f, 0.f, 0.f, 0.f};

        // ===== S1: conv im2col GEMM (M=64, N=32/wave, K per band), SW-pipelined B =====
        {
            const int lo = lo_kc[n], hi = hi_kc[n];
            const unsigned short* cw0 = cwF + ((size_t)((n * 8 + 2 * w)     * 16)) * 512;
            const unsigned short* cw1 = cwF + ((size_t)((n * 8 + 2 * w + 1) * 16)) * 512;
            const int scol = (quad & 1) * 8;
            v8s b0a = *reinterpret_cast<const v8s*>(cw0 + (size_t)lo * 512);
            v8s b0b = *reinterpret_cast<const v8s*>(cw1 + (size_t)lo * 512);
            for (int kc = lo; kc < hi; ++kc) {
                v8s b1a, b1b;
                if (kc + 1 < hi) {
                    b1a = *reinterpret_cast<const v8s*>(cw0 + (size_t)(kc + 1) * 512);
                    b1b = *reinterpret_cast<const v8s*>(cw1 + (size_t)(kc + 1) * 512);
                }
                const int tap = kc * 2 + (quad >> 1);
                #pragma unroll
                for (int mt = 0; mt < 4; mt++) {
                    v8s a = *reinterpret_cast<const v8s*>(&xw[(mt * 16 + l16 + tap) * XWS + scol]);
                    acc[mt][0] = __builtin_amdgcn_mfma_f32_16x16x32_bf16(a, b0a, acc[mt][0], 0, 0, 0);
                    acc[mt][1] = __builtin_amdgcn_mfma_f32_16x16x32_bf16(a, b0b, acc[mt][1], 0, 0, 0);
                }
                b0a = b1a; b0b = b1b;
            }
        }

        // ===== LN1 partials: h = acc + cb; write (Sh, Sh^2) per row per wave =====
        {
            const float cb0 = conv_b[n * 128 + col0];
            const float cb1 = conv_b[n * 128 + col1];
            #pragma unroll
            for (int mt = 0; mt < 4; mt++)
                #pragma unroll
                for (int r = 0; r < 4; r++) {
                    float h0 = acc[mt][0][r] + cb0;
                    float h1 = acc[mt][1][r] + cb1;
                    acc[mt][0][r] = h0; acc[mt][1][r] = h1;
                    float p1 = h0 + h1, p2 = h0 * h0 + h1 * h1;
                    p1 += __shfl_xor(p1, 1); p2 += __shfl_xor(p2, 1);
                    p1 += __shfl_xor(p1, 2); p2 += __shfl_xor(p2, 2);
                    p1 += __shfl_xor(p1, 4); p2 += __shfl_xor(p2, 4);
                    p1 += __shfl_xor(p1, 8); p2 += __shfl_xor(p2, 8);
                    if (l16 == 0) {
                        part1[(mt * 16 + quad * 4 + r) * 8 + w * 2]     = p1;
                        part1[(mt * 16 + quad * 4 + r) * 8 + w * 2 + 1] = p2;
                    }
                }
        }
        __syncthreads();   // B1

        // ===== LN1 apply (hn in regs) + LN2 partials =====
        {
            const float dg0 = dec_g[n * 128 + col0], db0 = dec_b[n * 128 + col0];
            const float dg1 = dec_g[n * 128 + col1], db1 = dec_b[n * 128 + col1];
            #pragma unroll
            for (int mt = 0; mt < 4; mt++)
                #pragma unroll
                for (int r = 0; r < 4; r++) {
                    const int row = mt * 16 + quad * 4 + r;
                    float4 q0 = *reinterpret_cast<const float4*>(&part1[row * 8]);
                    float4 q1 = *reinterpret_cast<const float4*>(&part1[row * 8 + 4]);
                    float s1 = q0.x + q0.z + q1.x + q1.z;
                    float s2 = q0.y + q0.w + q1.y + q1.w;
                    float mu = s1 * (1.f / 128.f);
                    float rs = rsqrtf(s2 * (1.f / 128.f) - mu * mu + 1e-5f);
                    float hn0 = (acc[mt][0][r] - mu) * rs * dg0 + db0;
                    float hn1 = (acc[mt][1][r] - mu) * rs * dg1 + db1;
                    acc[mt][0][r] = hn0; acc[mt][1][r] = hn1;
                    float p1 = hn0 + hn1, p2 = hn0 * hn0 + hn1 * hn1;
                    p1 += __shfl_xor(p1, 1); p2 += __shfl_xor(p2, 1);
                    p1 += __shfl_xor(p1, 2); p2 += __shfl_xor(p2, 2);
                    p1 += __shfl_xor(p1, 4); p2 += __shfl_xor(p2, 4);
                    p1 += __shfl_xor(p1, 8); p2 += __shfl_xor(p2, 8);
                    if (l16 == 0) {
                        part2[row * 8 + w * 2]     = p1;
                        part2[row * 8 + w * 2 + 1] = p2;
                    }
                }
        }
        __syncthreads();   // B2

        // ===== LN2 apply -> z to zbuf; pack hn residual =====
        {
            const float ng0 = n2_g[n * 128 + col0], nb0 = n2_b[n * 128 + col0];
            const float ng1 = n2_g[n * 128 + col1], nb1 = n2_b[n * 128 + col1];
            #pragma unroll
            for (int mt = 0; mt < 4; mt++)
                #pragma unroll
                for (int r = 0; r < 4; r++) {
                    const int row = mt * 16 + quad * 4 + r;
                    float4 q0 = *reinterpret_cast<const float4*>(&part2[row * 8]);
                    float4 q1 = *reinterpret_cast<const float4*>(&part2[row * 8 + 4]);
                    float s1 = q0.x + q0.z + q1.x + q1.z;
                    float s2 = q0.y + q0.w + q1.y + q1.w;
                    float mu2 = s1 * (1.f / 128.f);
                    float rs2 = rsqrtf(s2 * (1.f / 128.f) - mu2 * mu2 + 1e-5f);
                    float hn0 = acc[mt][0][r], hn1 = acc[mt][1][r];
                    zbuf[row * ZS + col0] = f2b((hn0 - mu2) * rs2 * ng0 + nb0);
                    zbuf[row * ZS + col1] = f2b((hn1 - mu2) * rs2 * ng1 + nb1);
                    hpk[mt * 4 + r] = (unsigned)f2b(hn0) | ((unsigned)f2b(hn1) << 16);
                }
        }
        __syncthreads();   // B3 (zbuf ready)

        // ===== FFN1 + gelu / FFN2, e-split halves (K=128 each) =====
        v4f acc2[4][2];
        #pragma unroll
        for (int mt = 0; mt < 4; mt++)
            #pragma unroll
            for (int c = 0; c < 2; c++) acc2[mt][c] = (v4f){0.f, 0.f, 0.f, 0.f};

        #pragma unroll
        for (int eh = 0; eh < 2; ++eh) {
            // FFN1: etiles eh*8+2w, eh*8+2w+1; preload 8 B-frags
            {
                v8s bf[2][4];
                #pragma unroll
                for (int c = 0; c < 2; c++)
                    #pragma unroll
                    for (int kb = 0; kb < 4; kb++)
                        bf[c][kb] = *reinterpret_cast<const v8s*>(
                            w1F + ((size_t)((n * 16 + eh * 8 + 2 * w + c) * 4 + kb)) * 512);
                v4f ua[4][2];
                #pragma unroll
                for (int mt = 0; mt < 4; mt++)
                    #pragma unroll
                    for (int c = 0; c < 2; c++) ua[mt][c] = (v4f){0.f, 0.f, 0.f, 0.f};
                #pragma unroll
                for (int kb = 0; kb < 4; kb++)
                    #pragma unroll
                    for (int mt = 0; mt < 4; mt++) {
                        v8s a = *reinterpret_cast<const v8s*>(&zbuf[(mt * 16 + l16) * ZS + kb * 32 + quad * 8]);
                        ua[mt][0] = __builtin_amdgcn_mfma_f32_16x16x32_bf16(a, bf[0][kb], ua[mt][0], 0, 0, 0);
                        ua[mt][1] = __builtin_amdgcn_mfma_f32_16x16x32_bf16(a, bf[1][kb], ua[mt][1], 0, 0, 0);
                    }
                const float b10 = ffn_b1[n * 256 + eh * 128 + w * 32 + l16];
                const float b11 = ffn_b1[n * 256 + eh * 128 + w * 32 + 16 + l16];
                #pragma unroll
                for (int mt = 0; mt < 4; mt++)
                    #pragma unroll
                    for (int r = 0; r < 4; r++) {
                        const int row = mt * 16 + quad * 4 + r;
                        ubuf[row * US + w * 32 + l16]      = f2b(gelu_fast(ua[mt][0][r] + b10));
                        ubuf[row * US + w * 32 + 16 + l16] = f2b(gelu_fast(ua[mt][1][r] + b11));
                    }
            }
            __syncthreads();   // u-half ready

            // FFN2 partial: dtiles 2w,2w+1; k-chunks eh*4..eh*4+3; preload 8 B-frags
            {
                v8s bf[2][4];
                #pragma unroll
                for (int c = 0; c < 2; c++)
                    #pragma unroll
                    for (int kb = 0; kb < 4; kb++)
                        bf[c][kb] = *reinterpret_cast<const v8s*>(
                            w2F + ((size_t)((n * 8 + 2 * w + c) * 8 + eh * 4 + kb)) * 512);
                #pragma unroll
                for (int kb = 0; kb < 4; kb++)
                    #pragma unroll
                    for (int mt = 0; mt < 4; mt++) {
                        v8s a = *reinterpret_cast<const v8s*>(&ubuf[(mt * 16 + l16) * US + kb * 32 + quad * 8]);
                        acc2[mt][0] = __builtin_amdgcn_mfma_f32_16x16x32_bf16(a, bf[0][kb], acc2[mt][0], 0, 0, 0);
                        acc2[mt][1] = __builtin_amdgcn_mfma_f32_16x16x32_bf16(a, bf[1][kb], acc2[mt][1], 0, 0, 0);
                    }
            }
            if (eh == 0) __syncthreads();   // u-half consumed before overwrite
        }

        // ===== band_out = acc2 + b2 + hn -> zbuf =====
        {
            const float b20 = ffn_b2[n * 128 + col0];
            const float b21 = ffn_b2[n * 128 + col1];
            #pragma unroll
            for (int mt = 0; mt < 4; mt++)
                #pragma unroll
                for (int r = 0; r < 4; r++) {
                    const int row = mt * 16 + quad * 4 + r;
                    unsigned hp = hpk[mt * 4 + r];
                    float hn0 = __uint_as_float(hp << 16);
                    float hn1 = __uint_as_float(hp & 0xffff0000u);
                    zbuf[row * ZS + col0] = f2b(acc2[mt][0][r] + b20 + hn0);
                    zbuf[row * ZS + col1] = f2b(acc2[mt][1][r] + b21 + hn1);
                }
        }
        __syncthreads();   // band_out ready

        // ===== proj (M=64, N=16/wave, K=128): j-tile w =====
        {
            v8s bf[4];
            #pragma unroll
            for (int kb = 0; kb < 4; kb++)
                bf[kb] = *reinterpret_cast<const v8s*>(
                    pF + ((size_t)((n * 4 + w) * 4 + kb)) * 512);
            v4f pa[4];
            #pragma unroll
            for (int mt = 0; mt < 4; mt++) pa[mt] = (v4f){0.f, 0.f, 0.f, 0.f};
            #pragma unroll
            for (int kb = 0; kb < 4; kb++)
                #pragma unroll
                for (int mt = 0; mt < 4; mt++) {
                    v8s a = *reinterpret_cast<const v8s*>(&zbuf[(mt * 16 + l16) * ZS + kb * 32 + quad * 8]);
                    pa[mt] = __builtin_amdgcn_mfma_f32_16x16x32_bf16(a, bf[kb], pa[mt], 0, 0, 0);
                }
            const float pbv = proj_b[n * 64 + w * 16 + l16];
            unsigned short* pb = ubuf;   // alias (u dead)
            #pragma unroll
            for (int mt = 0; mt < 4; mt++)
                #pragma unroll
                for (int r = 0; r < 4; r++)
                    pb[(mt * 16 + quad * 4 + r) * PS + w * 16 + l16] = f2b(pa[mt][r] + pbv);
        }
        __syncthreads();   // p ready

        // ===== mix1 partial accumulate (K=64): ctiles 2w,2w+1 =====
        {
            v8s bf[2][2];
            #pragma unroll
            for (int c = 0; c < 2; c++)
                #pragma unroll
                for (int kc = 0; kc < 2; kc++)
                    bf[c][kc] = *reinterpret_cast<const v8s*>(
                        m1F + ((size_t)(((2 * w + c) * 7 + n) * 2 + kc)) * 512);
            const unsigned short* pb = ubuf;
            #pragma unroll
            for (int kc = 0; kc < 2; kc++)
                #pragma unroll
                for (int mt = 0; mt < 4; mt++) {
                    v8s a = *reinterpret_cast<const v8s*>(&pb[(mt * 16 + l16) * PS + kc * 32 + quad * 8]);
                    macc[mt][0] = __builtin_amdgcn_mfma_f32_16x16x32_bf16(a, bf[0][kc], macc[mt][0], 0, 0, 0);
                    macc[mt][1] = __builtin_amdgcn_mfma_f32_16x16x32_bf16(a, bf[1][kc], macc[mt][1], 0, 0, 0);
                }
        }
        // no barrier: next band's part1 writes are many barriers away for any reader
    }

    // ===== m = gelu(macc + b1) -> zbuf =====
    #pragma unroll
    for (int c = 0; c < 2; c++) {
        const int col = (2 * w + c) * 16 + l16;
        const float mb1 = mix_b1[col];
        #pragma unroll
        for (int mt = 0; mt < 4; mt++)
            #pragma unroll
            for (int r = 0; r < 4; r++)
                zbuf[(mt * 16 + quad * 4 + r) * ZS + col] = f2b(gelu_exact(macc[mt][c][r] + mb1));
    }
    __syncthreads();

    // ===== mix2 (M=16/wave, N=16, K=128) -> out =====
    {
        v8s bf[4];
        #pragma unroll
        for (int kb = 0; kb < 4; kb++)
            bf[kb] = *reinterpret_cast<const v8s*>(m2F + (size_t)kb * 512);
        v4f oacc = (v4f){0.f, 0.f, 0.f, 0.f};
        #pragma unroll
        for (int kb = 0; kb < 4; kb++) {
            v8s a = *reinterpret_cast<const v8s*>(&zbuf[(w * 16 + l16) * ZS + kb * 32 + quad * 8]);
            oacc = __builtin_amdgcn_mfma_f32_16x16x32_bf16(a, bf[kb], oacc, 0, 0, 0);
        }
        const float ob = mix_b2[l16];
        #pragma unroll
        for (int r = 0; r < 4; r++) {
            const int row = w * 16 + quad * 4 + r;
            out[((long)bb * TT + t0 + row) * SIN + l16] = oacc[r] + ob;
        }
    }
}

// ---------------------------------------------------------------------------
extern "C" void kernel_launch(void* const* d_in, const int* in_sizes, int n_in,
                              void* d_out, int out_size, void* d_ws, size_t ws_size,
                              hipStream_t stream) {
    (void)in_sizes; (void)n_in; (void)out_size; (void)ws_size;
    const float* x      = (const float*)d_in[0];
    const float* conv_w = (const float*)d_in[1];
    const float* conv_b = (const float*)d_in[2];
    const float* dec_g  = (const float*)d_in[3];
    const float* dec_b  = (const float*)d_in[4];
    const float* n2_g   = (const float*)d_in[5];
    const float* n2_b   = (const float*)d_in[6];
    const float* ffn_w1 = (const float*)d_in[7];
    const float* ffn_b1 = (const float*)d_in[8];
    const float* ffn_w2 = (const float*)d_in[9];
    const float* ffn_b2 = (const float*)d_in[10];
    const float* proj_w = (const float*)d_in[11];
    const float* proj_b = (const float*)d_in[12];
    const float* mix_w1 = (const float*)d_in[13];
    const float* mix_b1 = (const float*)d_in[14];
    const float* mix_w2 = (const float*)d_in[15];
    const float* mix_b2 = (const float*)d_in[16];
    unsigned short* wsb = (unsigned short*)d_ws;
    float* out = (float*)d_out;

    hipLaunchKernelGGL(prep_weights, dim3(1024), dim3(256), 0, stream,
                       conv_w, ffn_w1, ffn_w2, proj_w, mix_w1, mix_w2, wsb);
    hipLaunchKernelGGL(fused_main, dim3(BB * (TT / TM)), dim3(256), 0, stream,
                       x, conv_b, dec_g, dec_b, n2_g, n2_b, ffn_b1, ffn_b2,
                       proj_b, mix_b1, mix_b2, wsb, out);
}

// Round 5
// 461.510 us; speedup vs baseline: 2.7413x; 1.6280x over previous
//
#include <hip/hip_runtime.h>
#include <stdint.h>

// ---------------------------------------------------------------------------
// Problem constants
// ---------------------------------------------------------------------------
#define NB   7
#define SIN  16
#define DD   128
#define BB   32
#define TT   2048
#define TM   64          // t-rows per block (4 waves, N-split over cols)
#define KMAX 31

#define XWS  24          // x window row stride (ushort); 48B rows
#define ZS   136         // z / bandout row stride
#define US   136         // u-half row stride (also m buffer)
#define PS   72          // p row stride

// Fragment-linear weight regions (ushort element offsets in ws).
// Every 512-element chunk is one wave B-fragment: [lane(64)][j(8)].
#define O_CWF 0           // [7][ntile 8][kc 16][512]
#define O_W1F 458752      // [7][etile 16][kb 4][512]
#define O_W2F 688128      // [7][dtile 8][kc 8][512]
#define O_PF  917504      // [7][jtile 4][kb 4][512]
#define O_M1F 974848      // [ctile 8][band 7][kc 2][512]
#define O_M2F 1032192     // [kb 4][512]
#define W_TOTAL 1034240

typedef short v8s __attribute__((ext_vector_type(8)));
typedef float v4f __attribute__((ext_vector_type(4)));

__device__ __forceinline__ unsigned short f2b(float f) {
    unsigned u = __float_as_uint(f);
    u += 0x7fffu + ((u >> 16) & 1u);          // round-to-nearest-even
    return (unsigned short)(u >> 16);
}
__device__ __forceinline__ float gelu_exact(float x) {  // exact erf gelu (matches reference)
    return 0.5f * x * (1.f + erff(x * 0.70710678118654752f));
}

// ---------------------------------------------------------------------------
// Weight prep: fp32 -> bf16, gathered into fragment-linear layout.
// ---------------------------------------------------------------------------
__global__ __launch_bounds__(256)
void prep_weights(const float* __restrict__ conv_w,
                  const float* __restrict__ ffn_w1,
                  const float* __restrict__ ffn_w2,
                  const float* __restrict__ proj_w,
                  const float* __restrict__ mix_w1,
                  const float* __restrict__ mix_w2,
                  unsigned short* __restrict__ wsb) {
    for (int i = blockIdx.x * 256 + threadIdx.x; i < W_TOTAL; i += gridDim.x * 256) {
        int o = i;
        int t9 = o & 511, j = t9 & 7, ln = t9 >> 3;
        int q = ln >> 4, l = ln & 15;
        float v;
        if (o < O_W1F) {                                   // conv
            int f = o >> 9;
            int band = f >> 7, rem = f & 127, ntile = rem >> 4, kc = rem & 15;
            int kg = kc * 32 + q * 8 + j, tap = kg >> 4, s = kg & 15, d = ntile * 16 + l;
            v = (tap < KMAX) ? conv_w[((band * KMAX + tap) * SIN + s) * DD + d] : 0.f;
        } else if (o < O_W2F) {                            // ffn_w1
            int f = (o - O_W1F) >> 9;
            int band = f >> 6, rem = f & 63, et = rem >> 2, kb = rem & 3;
            int k = kb * 32 + q * 8 + j, e = et * 16 + l;
            v = ffn_w1[(band * 128 + k) * 256 + e];
        } else if (o < O_PF) {                             // ffn_w2
            int f = (o - O_W2F) >> 9;
            int band = f >> 6, rem = f & 63, dt = rem >> 3, kc = rem & 7;
            int k = kc * 32 + q * 8 + j, d = dt * 16 + l;
            v = ffn_w2[(band * 256 + k) * 128 + d];
        } else if (o < O_M1F) {                            // proj
            int f = (o - O_PF) >> 9;
            int band = f >> 4, rem = f & 15, jt = rem >> 2, kb = rem & 3;
            int k = kb * 32 + q * 8 + j, c = jt * 16 + l;
            v = proj_w[(band * 128 + k) * 64 + c];
        } else if (o < O_M2F) {                            // mix_w1
            int f = (o - O_M1F) >> 9;
            int ct = f / 14, rem = f % 14, band = rem >> 1, kc = rem & 1;
            int k = band * 64 + kc * 32 + q * 8 + j, c = ct * 16 + l;
            v = mix_w1[k * 128 + c];
        } else {                                           // mix_w2
            int f = (o - O_M2F) >> 9;
            int k = f * 32 + q * 8 + j;
            v = mix_w2[k * SIN + l];
        }
        wsb[i] = f2b(v);
    }
}

// ---------------------------------------------------------------------------
// Fused main kernel. N-split: wave w owns cols w*32..w*32+31 of every stage.
// LN stats via 2-float cross-wave partials; h/hn stay in registers.
// __launch_bounds__(256,2): 256-reg unified budget — R2/R4 showed (256,3)
// splits to ~84 arch VGPRs and spills ~1.2 GB of scratch. DO NOT raise.
// ---------------------------------------------------------------------------
__global__ __launch_bounds__(256, 2)
void fused_main(const float* __restrict__ x,
                const float* __restrict__ conv_b,
                const float* __restrict__ dec_g, const float* __restrict__ dec_b,
                const float* __restrict__ n2_g,  const float* __restrict__ n2_b,
                const float* __restrict__ ffn_b1, const float* __restrict__ ffn_b2,
                const float* __restrict__ proj_b,
                const float* __restrict__ mix_b1, const float* __restrict__ mix_b2,
                const unsigned short* __restrict__ wsb,
                float* __restrict__ out) {
    __shared__ __align__(16) unsigned short xw[95 * XWS];     //  4,560 B
    __shared__ __align__(16) unsigned short zbuf[TM * ZS];    // 17,408 B (z / band_out)
    __shared__ __align__(16) unsigned short ubuf[TM * US];    // 17,408 B (u-half / p / m)
    __shared__ __align__(16) float part1[TM * 8];             //  2,048 B
    __shared__ __align__(16) float part2[TM * 8];             //  2,048 B

    const int tid  = threadIdx.x;
    const int lane = tid & 63;
    const int w    = tid >> 6;       // wave 0..3
    const int l16  = lane & 15;
    const int quad = lane >> 4;      // 0..3
    const int bb   = blockIdx.x >> 5;
    const int t0   = (blockIdx.x & 31) * TM;

    const unsigned short* cwF = wsb + O_CWF + lane * 8;
    const unsigned short* w1F = wsb + O_W1F + lane * 8;
    const unsigned short* w2F = wsb + O_W2F + lane * 8;
    const unsigned short* pF  = wsb + O_PF  + lane * 8;
    const unsigned short* m1F = wsb + O_M1F + lane * 8;
    const unsigned short* m2F = wsb + O_M2F + lane * 8;

    // ---- S0: stage x window (rows t0-15 .. t0+78), bf16 ----
    for (int i = tid; i < 95 * SIN; i += 256) {
        int r = i >> 4, s = i & 15;
        int t = t0 + r - 15;
        float v = (t >= 0 && t < TT) ? x[((long)bb * TT + t) * SIN + s] : 0.f;
        xw[r * XWS + s] = f2b(v);
    }

    v4f macc[4][2];                  // persistent mix1 accumulators (ctiles 2w,2w+1)
    #pragma unroll
    for (int mt = 0; mt < 4; mt++)
        #pragma unroll
        for (int c = 0; c < 2; c++) macc[mt][c] = (v4f){0.f, 0.f, 0.f, 0.f};

    __syncthreads();

    static const int lo_kc[NB] = {0, 2, 4, 5, 6, 6, 7};
    static const int hi_kc[NB] = {16, 13, 12, 11, 10, 9, 9};

    const int col0 = w * 32 + l16;       // nt=0 col for this lane
    const int col1 = col0 + 16;          // nt=1 col

    for (int n = 0; n < NB; ++n) {
        unsigned hpk[16];                // packed hn (residual), [mt*4+r] = (hn0 | hn1<<16)
        v4f acc[4][2];                   // conv C-frags -> h -> hn (in regs)
        #pragma unroll
        for (int mt = 0; mt < 4; mt++)
            #pragma unroll
            for (int c = 0; c < 2; c++) acc[mt][c] = (v4f){0.f, 0.f, 0.f, 0.f};

        // ===== S1: conv im2col GEMM (M=64, N=32/wave, K per band), SW-pipelined B =====
        {
            const int lo = lo_kc[n], hi = hi_kc[n];
            const unsigned short* cw0 = cwF + ((size_t)((n * 8 + 2 * w)     * 16)) * 512;
            const unsigned short* cw1 = cwF + ((size_t)((n * 8 + 2 * w + 1) * 16)) * 512;
            const int scol = (quad & 1) * 8;
            v8s b0a = *reinterpret_cast<const v8s*>(cw0 + (size_t)lo * 512);
            v8s b0b = *reinterpret_cast<const v8s*>(cw1 + (size_t)lo * 512);
            for (int kc = lo; kc < hi; ++kc) {
                v8s b1a, b1b;
                if (kc + 1 < hi) {
                    b1a = *reinterpret_cast<const v8s*>(cw0 + (size_t)(kc + 1) * 512);
                    b1b = *reinterpret_cast<const v8s*>(cw1 + (size_t)(kc + 1) * 512);
                }
                const int tap = kc * 2 + (quad >> 1);
                #pragma unroll
                for (int mt = 0; mt < 4; mt++) {
                    v8s a = *reinterpret_cast<const v8s*>(&xw[(mt * 16 + l16 + tap) * XWS + scol]);
                    acc[mt][0] = __builtin_amdgcn_mfma_f32_16x16x32_bf16(a, b0a, acc[mt][0], 0, 0, 0);
                    acc[mt][1] = __builtin_amdgcn_mfma_f32_16x16x32_bf16(a, b0b, acc[mt][1], 0, 0, 0);
                }
                b0a = b1a; b0b = b1b;
            }
        }

        // ===== LN1 partials: h = acc + cb; write (Sh, Sh^2) per row per wave =====
        {
            const float cb0 = conv_b[n * 128 + col0];
            const float cb1 = conv_b[n * 128 + col1];
            #pragma unroll
            for (int mt = 0; mt < 4; mt++)
                #pragma unroll
                for (int r = 0; r < 4; r++) {
                    float h0 = acc[mt][0][r] + cb0;
                    float h1 = acc[mt][1][r] + cb1;
                    acc[mt][0][r] = h0; acc[mt][1][r] = h1;
                    float p1 = h0 + h1, p2 = h0 * h0 + h1 * h1;
                    p1 += __shfl_xor(p1, 1); p2 += __shfl_xor(p2, 1);
                    p1 += __shfl_xor(p1, 2); p2 += __shfl_xor(p2, 2);
                    p1 += __shfl_xor(p1, 4); p2 += __shfl_xor(p2, 4);
                    p1 += __shfl_xor(p1, 8); p2 += __shfl_xor(p2, 8);
                    if (l16 == 0) {
                        part1[(mt * 16 + quad * 4 + r) * 8 + w * 2]     = p1;
                        part1[(mt * 16 + quad * 4 + r) * 8 + w * 2 + 1] = p2;
                    }
                }
        }
        __syncthreads();   // B1

        // ===== LN1 apply (hn in regs) + LN2 partials =====
        {
            const float dg0 = dec_g[n * 128 + col0], db0 = dec_b[n * 128 + col0];
            const float dg1 = dec_g[n * 128 + col1], db1 = dec_b[n * 128 + col1];
            #pragma unroll
            for (int mt = 0; mt < 4; mt++)
                #pragma unroll
                for (int r = 0; r < 4; r++) {
                    const int row = mt * 16 + quad * 4 + r;
                    float4 q0 = *reinterpret_cast<const float4*>(&part1[row * 8]);
                    float4 q1 = *reinterpret_cast<const float4*>(&part1[row * 8 + 4]);
                    float s1 = q0.x + q0.z + q1.x + q1.z;
                    float s2 = q0.y + q0.w + q1.y + q1.w;
                    float mu = s1 * (1.f / 128.f);
                    float rs = rsqrtf(s2 * (1.f / 128.f) - mu * mu + 1e-5f);
                    float hn0 = (acc[mt][0][r] - mu) * rs * dg0 + db0;
                    float hn1 = (acc[mt][1][r] - mu) * rs * dg1 + db1;
                    acc[mt][0][r] = hn0; acc[mt][1][r] = hn1;
                    float p1 = hn0 + hn1, p2 = hn0 * hn0 + hn1 * hn1;
                    p1 += __shfl_xor(p1, 1); p2 += __shfl_xor(p2, 1);
                    p1 += __shfl_xor(p1, 2); p2 += __shfl_xor(p2, 2);
                    p1 += __shfl_xor(p1, 4); p2 += __shfl_xor(p2, 4);
                    p1 += __shfl_xor(p1, 8); p2 += __shfl_xor(p2, 8);
                    if (l16 == 0) {
                        part2[row * 8 + w * 2]     = p1;
                        part2[row * 8 + w * 2 + 1] = p2;
                    }
                }
        }
        __syncthreads();   // B2

        // ===== LN2 apply -> z to zbuf; pack hn residual =====
        {
            const float ng0 = n2_g[n * 128 + col0], nb0 = n2_b[n * 128 + col0];
            const float ng1 = n2_g[n * 128 + col1], nb1 = n2_b[n * 128 + col1];
            #pragma unroll
            for (int mt = 0; mt < 4; mt++)
                #pragma unroll
                for (int r = 0; r < 4; r++) {
                    const int row = mt * 16 + quad * 4 + r;
                    float4 q0 = *reinterpret_cast<const float4*>(&part2[row * 8]);
                    float4 q1 = *reinterpret_cast<const float4*>(&part2[row * 8 + 4]);
                    float s1 = q0.x + q0.z + q1.x + q1.z;
                    float s2 = q0.y + q0.w + q1.y + q1.w;
                    float mu2 = s1 * (1.f / 128.f);
                    float rs2 = rsqrtf(s2 * (1.f / 128.f) - mu2 * mu2 + 1e-5f);
                    float hn0 = acc[mt][0][r], hn1 = acc[mt][1][r];
                    zbuf[row * ZS + col0] = f2b((hn0 - mu2) * rs2 * ng0 + nb0);
                    zbuf[row * ZS + col1] = f2b((hn1 - mu2) * rs2 * ng1 + nb1);
                    hpk[mt * 4 + r] = (unsigned)f2b(hn0) | ((unsigned)f2b(hn1) << 16);
                }
        }
        __syncthreads();   // B3 (zbuf ready)

        // ===== FFN1 + gelu / FFN2, e-split halves (K=128 each) =====
        v4f acc2[4][2];
        #pragma unroll
        for (int mt = 0; mt < 4; mt++)
            #pragma unroll
            for (int c = 0; c < 2; c++) acc2[mt][c] = (v4f){0.f, 0.f, 0.f, 0.f};

        #pragma unroll
        for (int eh = 0; eh < 2; ++eh) {
            // FFN1: etiles eh*8+2w, eh*8+2w+1; preload 8 B-frags
            {
                v8s bf[2][4];
                #pragma unroll
                for (int c = 0; c < 2; c++)
                    #pragma unroll
                    for (int kb = 0; kb < 4; kb++)
                        bf[c][kb] = *reinterpret_cast<const v8s*>(
                            w1F + ((size_t)((n * 16 + eh * 8 + 2 * w + c) * 4 + kb)) * 512);
                v4f ua[4][2];
                #pragma unroll
                for (int mt = 0; mt < 4; mt++)
                    #pragma unroll
                    for (int c = 0; c < 2; c++) ua[mt][c] = (v4f){0.f, 0.f, 0.f, 0.f};
                #pragma unroll
                for (int kb = 0; kb < 4; kb++)
                    #pragma unroll
                    for (int mt = 0; mt < 4; mt++) {
                        v8s a = *reinterpret_cast<const v8s*>(&zbuf[(mt * 16 + l16) * ZS + kb * 32 + quad * 8]);
                        ua[mt][0] = __builtin_amdgcn_mfma_f32_16x16x32_bf16(a, bf[0][kb], ua[mt][0], 0, 0, 0);
                        ua[mt][1] = __builtin_amdgcn_mfma_f32_16x16x32_bf16(a, bf[1][kb], ua[mt][1], 0, 0, 0);
                    }
                const float b10 = ffn_b1[n * 256 + eh * 128 + w * 32 + l16];
                const float b11 = ffn_b1[n * 256 + eh * 128 + w * 32 + 16 + l16];
                #pragma unroll
                for (int mt = 0; mt < 4; mt++)
                    #pragma unroll
                    for (int r = 0; r < 4; r++) {
                        const int row = mt * 16 + quad * 4 + r;
                        ubuf[row * US + w * 32 + l16]      = f2b(gelu_exact(ua[mt][0][r] + b10));
                        ubuf[row * US + w * 32 + 16 + l16] = f2b(gelu_exact(ua[mt][1][r] + b11));
                    }
            }
            __syncthreads();   // u-half ready

            // FFN2 partial: dtiles 2w,2w+1; k-chunks eh*4..eh*4+3; preload 8 B-frags
            {
                v8s bf[2][4];
                #pragma unroll
                for (int c = 0; c < 2; c++)
                    #pragma unroll
                    for (int kb = 0; kb < 4; kb++)
                        bf[c][kb] = *reinterpret_cast<const v8s*>(
                            w2F + ((size_t)((n * 8 + 2 * w + c) * 8 + eh * 4 + kb)) * 512);
                #pragma unroll
                for (int kb = 0; kb < 4; kb++)
                    #pragma unroll
                    for (int mt = 0; mt < 4; mt++) {
                        v8s a = *reinterpret_cast<const v8s*>(&ubuf[(mt * 16 + l16) * US + kb * 32 + quad * 8]);
                        acc2[mt][0] = __builtin_amdgcn_mfma_f32_16x16x32_bf16(a, bf[0][kb], acc2[mt][0], 0, 0, 0);
                        acc2[mt][1] = __builtin_amdgcn_mfma_f32_16x16x32_bf16(a, bf[1][kb], acc2[mt][1], 0, 0, 0);
                    }
            }
            if (eh == 0) __syncthreads();   // u-half consumed before overwrite
        }

        // ===== band_out = acc2 + b2 + hn -> zbuf =====
        {
            const float b20 = ffn_b2[n * 128 + col0];
            const float b21 = ffn_b2[n * 128 + col1];
            #pragma unroll
            for (int mt = 0; mt < 4; mt++)
                #pragma unroll
                for (int r = 0; r < 4; r++) {
                    const int row = mt * 16 + quad * 4 + r;
                    unsigned hp = hpk[mt * 4 + r];
                    float hn0 = __uint_as_float(hp << 16);
                    float hn1 = __uint_as_float(hp & 0xffff0000u);
                    zbuf[row * ZS + col0] = f2b(acc2[mt][0][r] + b20 + hn0);
                    zbuf[row * ZS + col1] = f2b(acc2[mt][1][r] + b21 + hn1);
                }
        }
        __syncthreads();   // band_out ready

        // ===== proj (M=64, N=16/wave, K=128): j-tile w =====
        {
            v8s bf[4];
            #pragma unroll
            for (int kb = 0; kb < 4; kb++)
                bf[kb] = *reinterpret_cast<const v8s*>(
                    pF + ((size_t)((n * 4 + w) * 4 + kb)) * 512);
            v4f pa[4];
            #pragma unroll
            for (int mt = 0; mt < 4; mt++) pa[mt] = (v4f){0.f, 0.f, 0.f, 0.f};
            #pragma unroll
            for (int kb = 0; kb < 4; kb++)
                #pragma unroll
                for (int mt = 0; mt < 4; mt++) {
                    v8s a = *reinterpret_cast<const v8s*>(&zbuf[(mt * 16 + l16) * ZS + kb * 32 + quad * 8]);
                    pa[mt] = __builtin_amdgcn_mfma_f32_16x16x32_bf16(a, bf[kb], pa[mt], 0, 0, 0);
                }
            const float pbv = proj_b[n * 64 + w * 16 + l16];
            unsigned short* pb = ubuf;   // alias (u dead)
            #pragma unroll
            for (int mt = 0; mt < 4; mt++)
                #pragma unroll
                for (int r = 0; r < 4; r++)
                    pb[(mt * 16 + quad * 4 + r) * PS + w * 16 + l16] = f2b(pa[mt][r] + pbv);
        }
        __syncthreads();   // p ready

        // ===== mix1 partial accumulate (K=64): ctiles 2w,2w+1 =====
        {
            v8s bf[2][2];
            #pragma unroll
            for (int c = 0; c < 2; c++)
                #pragma unroll
                for (int kc = 0; kc < 2; kc++)
                    bf[c][kc] = *reinterpret_cast<const v8s*>(
                        m1F + ((size_t)(((2 * w + c) * 7 + n) * 2 + kc)) * 512);
            const unsigned short* pb = ubuf;
            #pragma unroll
            for (int kc = 0; kc < 2; kc++)
                #pragma unroll
                for (int mt = 0; mt < 4; mt++) {
                    v8s a = *reinterpret_cast<const v8s*>(&pb[(mt * 16 + l16) * PS + kc * 32 + quad * 8]);
                    macc[mt][0] = __builtin_amdgcn_mfma_f32_16x16x32_bf16(a, bf[0][kc], macc[mt][0], 0, 0, 0);
                    macc[mt][1] = __builtin_amdgcn_mfma_f32_16x16x32_bf16(a, bf[1][kc], macc[mt][1], 0, 0, 0);
                }
        }
        // no barrier: next band's part1 writes are ≥2 barriers away for any reader
    }

    // ===== m = gelu(macc + b1) -> zbuf =====
    #pragma unroll
    for (int c = 0; c < 2; c++) {
        const int col = (2 * w + c) * 16 + l16;
        const float mb1 = mix_b1[col];
        #pragma unroll
        for (int mt = 0; mt < 4; mt++)
            #pragma unroll
            for (int r = 0; r < 4; r++)
                zbuf[(mt * 16 + quad * 4 + r) * ZS + col] = f2b(gelu_exact(macc[mt][c][r] + mb1));
    }
    __syncthreads();

    // ===== mix2 (M=16/wave, N=16, K=128) -> out =====
    {
        v8s bf[4];
        #pragma unroll
        for (int kb = 0; kb < 4; kb++)
            bf[kb] = *reinterpret_cast<const v8s*>(m2F + (size_t)kb * 512);
        v4f oacc = (v4f){0.f, 0.f, 0.f, 0.f};
        #pragma unroll
        for (int kb = 0; kb < 4; kb++) {
            v8s a = *reinterpret_cast<const v8s*>(&zbuf[(w * 16 + l16) * ZS + kb * 32 + quad * 8]);
            oacc = __builtin_amdgcn_mfma_f32_16x16x32_bf16(a, bf[kb], oacc, 0, 0, 0);
        }
        const float ob = mix_b2[l16];
        #pragma unroll
        for (int r = 0; r < 4; r++) {
            const int row = w * 16 + quad * 4 + r;
            out[((long)bb * TT + t0 + row) * SIN + l16] = oacc[r] + ob;
        }
    }
}

// ---------------------------------------------------------------------------
extern "C" void kernel_launch(void* const* d_in, const int* in_sizes, int n_in,
                              void* d_out, int out_size, void* d_ws, size_t ws_size,
                              hipStream_t stream) {
    (void)in_sizes; (void)n_in; (void)out_size; (void)ws_size;
    const float* x      = (const float*)d_in[0];
    const float* conv_w = (const float*)d_in[1];
    const float* conv_b = (const float*)d_in[2];
    const float* dec_g  = (const float*)d_in[3];
    const float* dec_b  = (const float*)d_in[4];
    const float* n2_g   = (const float*)d_in[5];
    const float* n2_b   = (const float*)d_in[6];
    const float* ffn_w1 = (const float*)d_in[7];
    const float* ffn_b1 = (const float*)d_in[8];
    const float* ffn_w2 = (const float*)d_in[9];
    const float* ffn_b2 = (const float*)d_in[10];
    const float* proj_w = (const float*)d_in[11];
    const float* proj_b = (const float*)d_in[12];
    const float* mix_w1 = (const float*)d_in[13];
    const float* mix_b1 = (const float*)d_in[14];
    const float* mix_w2 = (const float*)d_in[15];
    const float* mix_b2 = (const float*)d_in[16];
    unsigned short* wsb = (unsigned short*)d_ws;
    float* out = (float*)d_out;

    hipLaunchKernelGGL(prep_weights, dim3(1024), dim3(256), 0, stream,
                       conv_w, ffn_w1, ffn_w2, proj_w, mix_w1, mix_w2, wsb);
    hipLaunchKernelGGL(fused_main, dim3(BB * (TT / TM)), dim3(256), 0, stream,
                       x, conv_b, dec_g, dec_b, n2_g, n2_b, ffn_b1, ffn_b2,
                       proj_b, mix_b1, mix_b2, wsb, out);
}